// Round 13
// baseline (107.046 us; speedup 1.0000x reference)
//
#include <hip/hip_runtime.h>
#include <stdint.h>

// TopKLayer quirky sparse_hw: per row (3136 elems), t = spatial index of the
// k-th largest |x| (k=313, ties ascending index); keep the t smallest-|x|
// elements (stable). 128-thread block per row, row pinned in registers (asm
// fence). TWO INDEPENDENT WAVES: each wave redundantly pulls the full packed
// 2048-bin histogram (pad-every-16 -> conflict-free) and computes the whole
// CDF + locate with wave ops only (no cross-wave scan). Per-wave compaction
// segments with per-wave counters. 6 barriers/row. launch_bounds(128,8).

#define HW    3136
#define NT    128
#define KSEL  313u
#define CAPH  256u       // candidate capacity per wave segment
#define CAP2  64u        // tie-set capacity
#define M31   0x7fffffffu
#define SENT  0xFFFFFFFFu

// LDS layout (words)
#define O_H    0         // 1088 = 1024 packed-u16 words + pad every 16
#define O_CAND 1088      // 512: segment 0 at +0, segment 1 at +CAPH
#define O_HC   1600      // 256
#define O_TINY 1856      // 64
#define O_CNT  1920      // 2 per-wave counters
#define O_RES  1922      // 1 result word
#define LDSW   1924

__device__ __forceinline__ unsigned wscan_incl(unsigned v) {
    const int lane = threadIdx.x & 63;
#pragma unroll
    for (int d = 1; d < 64; d <<= 1) {
        unsigned o = __shfl_up(v, d, 64);
        if (lane >= d) v += o;
    }
    return v;
}

__device__ __forceinline__ unsigned bcast_first(unsigned flag, unsigned val) {
    unsigned long long bal = __ballot(flag != 0);
    if (!bal) return 0u;
    return __shfl(val, __ffsll(bal) - 1, 64);
}

// packed u16 histogram with pad-every-16-words addressing
__device__ __forceinline__ void hadd(unsigned* h, unsigned b) {
    const unsigned w = b >> 1;
    atomicAdd(&h[w + (w >> 4)], (b & 1) ? 0x10000u : 1u);
}

// Locate bin holding dir-rank `rank` from per-lane packed counts pc[16]
// (lane owns bins 32*lane..32*lane+31); base = exclusive CDF of bin 32*lane.
// Returns (bin<<16)|m broadcast to all lanes; 0 if rank==0 (no hit).
template <bool fromTop>
__device__ __forceinline__ unsigned locate2048(const unsigned* pc, unsigned base,
                                               unsigned rank) {
    const int lane = threadIdx.x & 63;
    unsigned run = base, packed = 0;
#pragma unroll
    for (int j = 0; j < 16; ++j) {
        const unsigned lo = pc[j] & 0xFFFFu, hi = pc[j] >> 16;
        if (fromTop) {
            unsigned suf = HW - run - lo;
            if (suf < rank && rank <= suf + lo)
                packed = ((32u * lane + 2u * j) << 16) | (rank - suf);
            run += lo;
            suf = HW - run - hi;
            if (suf < rank && rank <= suf + hi)
                packed = ((32u * lane + 2u * j + 1u) << 16) | (rank - suf);
            run += hi;
        } else {
            if (run < rank && rank <= run + lo)
                packed = ((32u * lane + 2u * j) << 16) | (rank - run);
            run += lo;
            if (run < rank && rank <= run + hi)
                packed = ((32u * lane + 2u * j + 1u) << 16) | (rank - run);
            run += hi;
        }
    }
    return bcast_first(packed, packed);
}

// Wave0-only finish: subhist over both candidate segments, locate, tie-rank.
// Returns composite (low20<<12)|idx, or SENT (overflow), or 0 (m1==0).
template <bool fromTop>
__device__ unsigned wave_finish(unsigned* lds, unsigned m1) {
    const int lane = threadIdx.x & 63;
    unsigned* cand = lds + O_CAND;
    unsigned* hc   = lds + O_HC;
    unsigned* tiny = lds + O_TINY;
    const unsigned c0 = lds[O_CNT], c1 = lds[O_CNT + 1];
    if (m1 == 0) return 0u;
    if (c0 > CAPH || c1 > CAPH) return SENT;
    const unsigned cnt = c0 + c1;
#pragma unroll
    for (int i = 0; i < 4; ++i) hc[lane + 64 * i] = 0;
    for (unsigned i = lane; i < c0; i += 64) atomicAdd(&hc[cand[i] >> 24], 1u);
    for (unsigned i = lane; i < c1; i += 64) atomicAdd(&hc[cand[CAPH + i] >> 24], 1u);
    unsigned hh[4];
#pragma unroll
    for (int i = 0; i < 4; ++i) hh[i] = hc[4 * lane + i];
    const unsigned s4 = hh[0] + hh[1] + hh[2] + hh[3];
    unsigned run2 = wscan_incl(s4) - s4;
    unsigned packed2 = 0;
#pragma unroll
    for (int i = 0; i < 4; ++i) {
        if (fromTop) {
            const unsigned suf = cnt - run2 - hh[i];
            if (suf < m1 && m1 <= suf + hh[i])
                packed2 = ((unsigned)(4 * lane + i) << 16) | (m1 - suf);
        } else {
            if (run2 < m1 && m1 <= run2 + hh[i])
                packed2 = ((unsigned)(4 * lane + i) << 16) | (m1 - run2);
        }
        run2 += hh[i];
    }
    packed2 = bcast_first(packed2, packed2);
    if (packed2 == 0) return 0u;
    const unsigned b2 = packed2 >> 16;
    const unsigned m2 = packed2 & 0xFFFFu;
    unsigned tc = 0;
    for (unsigned i = lane; i < c0; i += 64) tc += ((cand[i] >> 24) == b2);
    for (unsigned i = lane; i < c1; i += 64) tc += ((cand[CAPH + i] >> 24) == b2);
    const unsigned tincl = wscan_incl(tc);
    const unsigned c2 = __shfl((int)tincl, 63, 64);
    if (c2 > CAP2) return SENT;
    unsigned tpos = tincl - tc;
    for (unsigned i = lane; i < c0; i += 64) {
        const unsigned cw = cand[i];
        if ((cw >> 24) == b2) tiny[tpos++] = cw;
    }
    for (unsigned i = lane; i < c1; i += 64) {
        const unsigned cw = cand[CAPH + i];
        if ((cw >> 24) == b2) tiny[tpos++] = cw;
    }
    unsigned hitf = 0, resv = 0;
    if ((unsigned)lane < c2) {
        const unsigned ci = tiny[lane];
        const unsigned di = fromTop ? (ci ^ 0xFFFu) : ci;
        unsigned r = 1;
        for (unsigned j = 0; j < c2; ++j) {
            const unsigned dj = fromTop ? (tiny[j] ^ 0xFFFu) : tiny[j];
            if (fromTop ? (dj > di) : (dj < di)) r++;
        }
        if (r == m2) { hitf = 1; resv = ci; }
    }
    return bcast_first(hitf, resv);
}

// Pathological fallback: bin-filtered counting rank over global row.
template <bool fromTop>
__device__ void block_fallback(const unsigned* __restrict__ gx,
                               unsigned b0, unsigned m1, unsigned* res) {
    const int t = threadIdx.x;
    for (int j = t; j < HW; j += NT) {
        const unsigned k = gx[j] & M31;
        if ((k >> 20) != b0) continue;
        unsigned Ci = ((k & 0xFFFFFu) << 12) | (unsigned)j;
        if (fromTop) Ci ^= 0xFFFu;
        unsigned r = 1;
        for (int j2 = 0; j2 < HW; ++j2) {
            const unsigned k2 = gx[j2] & M31;
            if ((k2 >> 20) != b0) continue;
            unsigned Cj = ((k2 & 0xFFFFFu) << 12) | (unsigned)j2;
            if (fromTop) Cj ^= 0xFFFu;
            if (fromTop ? (Cj > Ci) : (Cj < Ci)) r++;
        }
        if (r == m1) res[0] = ((k & 0xFFFFFu) << 12) | (unsigned)j;
    }
}

extern "C" __global__ void __launch_bounds__(NT, 8)
topk_kernel(const float* __restrict__ x, float* __restrict__ out) {
    __shared__ unsigned lds[LDSW];

    const int t = threadIdx.x;
    const int lane = t & 63;
    const int wid = t >> 6;
    const size_t row = blockIdx.x;
    const uint4* __restrict__ xin = (const uint4*)(x + row * HW);
    uint4* __restrict__ xo = (uint4*)(out + row * HW);
    const unsigned* __restrict__ gx = (const unsigned*)xin;
    const uint4 z4 = make_uint4(0u, 0u, 0u, 0u);

    // load row into registers; fence blocks rematerialization-as-reload
    uint4 v[6];
#pragma unroll
    for (int i = 0; i < 6; ++i) v[i] = xin[t + NT * i];
    uint4 vt = (t < 16) ? xin[768 + t] : z4;
#pragma unroll
    for (int i = 0; i < 6; ++i)
        asm volatile("" : "+v"(v[i].x), "+v"(v[i].y), "+v"(v[i].z), "+v"(v[i].w));
    asm volatile("" : "+v"(vt.x), "+v"(vt.y), "+v"(vt.z), "+v"(vt.w));

    // clear hist region (1088 words)
    for (int i = t; i < 1088; i += NT) lds[O_H + i] = 0;
    __syncthreads();                                         // B1

    // histogram from registers (abs bits 30:20)
#pragma unroll
    for (int i = 0; i < 6; ++i) {
        hadd(lds, (v[i].x & M31) >> 20); hadd(lds, (v[i].y & M31) >> 20);
        hadd(lds, (v[i].z & M31) >> 20); hadd(lds, (v[i].w & M31) >> 20);
    }
    if (t < 16) {
        hadd(lds, (vt.x & M31) >> 20); hadd(lds, (vt.y & M31) >> 20);
        hadd(lds, (vt.z & M31) >> 20); hadd(lds, (vt.w & M31) >> 20);
    }
    __syncthreads();                                         // B2

    // per-wave full CDF pull (conflict-free: addr 17*lane + j) + locate A
    unsigned pc[16];
#pragma unroll
    for (int j = 0; j < 16; ++j) pc[j] = lds[O_H + 17 * lane + j];
    unsigned ssum = 0;
#pragma unroll
    for (int j = 0; j < 16; ++j) ssum += (pc[j] & 0xFFFFu) + (pc[j] >> 16);
    const unsigned base = wscan_incl(ssum) - ssum;   // excl CDF of bin 32*lane
    const unsigned pA = locate2048<true>(pc, base, KSEL);
    const unsigned b0A = pA >> 16, m1A = pA & 0xFFFFu;

    // compact A into own wave segment (own counter; wave-internal ordering)
    unsigned* cseg = lds + O_CAND + wid * CAPH;
    unsigned* cctr = lds + O_CNT + wid;
    auto compact_regs = [&](unsigned b0) {
        auto cput = [&](unsigned wv, unsigned idx) {
            const unsigned k = wv & M31;
            if ((k >> 20) == b0) {
                const unsigned p = atomicAdd(cctr, 1u);
                if (p < CAPH) cseg[p] = ((k & 0xFFFFFu) << 12) | idx;
            }
        };
#pragma unroll
        for (int i = 0; i < 6; ++i) {
            const unsigned i0 = 4u * (unsigned)(t + NT * i);
            cput(v[i].x, i0); cput(v[i].y, i0 + 1u);
            cput(v[i].z, i0 + 2u); cput(v[i].w, i0 + 3u);
        }
        if (t < 16) {
            const unsigned i0 = 4u * (unsigned)(768 + t);
            cput(vt.x, i0); cput(vt.y, i0 + 1u);
            cput(vt.z, i0 + 2u); cput(vt.w, i0 + 3u);
        }
    };
    if (lane == 0) *cctr = 0;
    compact_regs(b0A);
    __syncthreads();                                         // B3

    if (wid == 0) {
        const unsigned r = wave_finish<true>(lds, m1A);
        if (lane == 0) lds[O_RES] = r;
    }
    __syncthreads();                                         // B4
    unsigned compA = lds[O_RES];
    if (compA == SENT) {
        block_fallback<true>(gx, b0A, m1A, lds + O_RES);
        __syncthreads();
        compA = lds[O_RES];
    }
    const unsigned tIdx = compA & 0xFFFu;

    // locate B: re-read intact hist (cand/hc/tiny live elsewhere)
#pragma unroll
    for (int j = 0; j < 16; ++j) pc[j] = lds[O_H + 17 * lane + j];
    const unsigned pB = locate2048<false>(pc, base, tIdx);   // 0 if tIdx==0
    const unsigned b0B = pB >> 16, m1B = pB & 0xFFFFu;

    if (lane == 0) *cctr = 0;
    compact_regs(b0B);
    __syncthreads();                                         // B5

    if (wid == 0) {
        const unsigned r = wave_finish<false>(lds, m1B);
        if (lane == 0) lds[O_RES] = r;
    }
    __syncthreads();                                         // B6
    unsigned compB = lds[O_RES];
    if (compB == SENT) {
        block_fallback<false>(gx, b0B, m1B, lds + O_RES);
        __syncthreads();
        compB = lds[O_RES];
    }
    const unsigned KB = (b0B << 20) | (compB >> 12);
    const unsigned eB = compB & 0xFFFu;

    // mask + store from registers: keep = k < KB || (k == KB && idx <= eB)
    {
        auto msk = [&](unsigned wv, unsigned idx) -> unsigned {
            const unsigned k = wv & M31;
            return (k < KB || (k == KB && idx <= eB)) ? wv : 0u;
        };
#pragma unroll
        for (int i = 0; i < 6; ++i) {
            const unsigned i0 = 4u * (unsigned)(t + NT * i);
            uint4 o = v[i];
            o.x = msk(o.x, i0); o.y = msk(o.y, i0 + 1u);
            o.z = msk(o.z, i0 + 2u); o.w = msk(o.w, i0 + 3u);
            xo[t + NT * i] = o;
        }
        if (t < 16) {
            const unsigned i0 = 4u * (unsigned)(768 + t);
            uint4 o = vt;
            o.x = msk(o.x, i0); o.y = msk(o.y, i0 + 1u);
            o.z = msk(o.z, i0 + 2u); o.w = msk(o.w, i0 + 3u);
            xo[768 + t] = o;
        }
    }
}

extern "C" void kernel_launch(void* const* d_in, const int* in_sizes, int n_in,
                              void* d_out, int out_size, void* d_ws, size_t ws_size,
                              hipStream_t stream) {
    const float* x = (const float*)d_in[0];
    float* out = (float*)d_out;
    const int rows = in_sizes[0] / HW;          // 8192
    topk_kernel<<<dim3(rows), dim3(NT), 0, stream>>>(x, out);
}

// Round 14
// 67.793 us; speedup vs baseline: 1.5790x; 1.5790x over previous
//
#include <hip/hip_runtime.h>
#include <stdint.h>

// TopKLayer quirky sparse_hw: per row (3136 elems), t = spatial index of the
// k-th largest |x| (k=313, ties ascending index); keep the t smallest-|x|
// elements (stable). 128-thread block per row, row pinned in registers (asm
// fence). Two waves: each redundantly pulls the full packed 2048-bin
// histogram (pad-every-16 -> conflict-free) and locates with wave ops only.
// Per-wave compaction segments/counters. 6 barriers/row.
// launch_bounds(128,6): VGPR budget ~84 fits row(25)+CDF(16) WITHOUT spill
// (R13's (128,8) cap of 64 caused scratch spill: FETCH 50->110MB).

#define HW    3136
#define NT    128
#define KSEL  313u
#define CAPH  256u       // candidate capacity per wave segment
#define CAP2  64u        // tie-set capacity
#define M31   0x7fffffffu
#define SENT  0xFFFFFFFFu

// LDS layout (words)
#define O_H    0         // 1088 = 1024 packed-u16 words + pad every 16
#define O_CAND 1088      // 512: segment 0 at +0, segment 1 at +CAPH
#define O_HC   1600      // 256
#define O_TINY 1856      // 64
#define O_CNT  1920      // 2 per-wave counters
#define O_RES  1922      // 1 result word
#define LDSW   1924

__device__ __forceinline__ unsigned wscan_incl(unsigned v) {
    const int lane = threadIdx.x & 63;
#pragma unroll
    for (int d = 1; d < 64; d <<= 1) {
        unsigned o = __shfl_up(v, d, 64);
        if (lane >= d) v += o;
    }
    return v;
}

__device__ __forceinline__ unsigned bcast_first(unsigned flag, unsigned val) {
    unsigned long long bal = __ballot(flag != 0);
    if (!bal) return 0u;
    return __shfl(val, __ffsll(bal) - 1, 64);
}

// packed u16 histogram with pad-every-16-words addressing
__device__ __forceinline__ void hadd(unsigned* h, unsigned b) {
    const unsigned w = b >> 1;
    atomicAdd(&h[w + (w >> 4)], (b & 1) ? 0x10000u : 1u);
}

// Locate bin holding dir-rank `rank` from per-lane packed counts pc[16]
// (lane owns bins 32*lane..32*lane+31); base = exclusive CDF of bin 32*lane.
// Returns (bin<<16)|m broadcast to all lanes; 0 if rank==0 (no hit).
template <bool fromTop>
__device__ __forceinline__ unsigned locate2048(const unsigned* pc, unsigned base,
                                               unsigned rank) {
    const int lane = threadIdx.x & 63;
    unsigned run = base, packed = 0;
#pragma unroll
    for (int j = 0; j < 16; ++j) {
        const unsigned lo = pc[j] & 0xFFFFu, hi = pc[j] >> 16;
        if (fromTop) {
            unsigned suf = HW - run - lo;
            if (suf < rank && rank <= suf + lo)
                packed = ((32u * lane + 2u * j) << 16) | (rank - suf);
            run += lo;
            suf = HW - run - hi;
            if (suf < rank && rank <= suf + hi)
                packed = ((32u * lane + 2u * j + 1u) << 16) | (rank - suf);
            run += hi;
        } else {
            if (run < rank && rank <= run + lo)
                packed = ((32u * lane + 2u * j) << 16) | (rank - run);
            run += lo;
            if (run < rank && rank <= run + hi)
                packed = ((32u * lane + 2u * j + 1u) << 16) | (rank - run);
            run += hi;
        }
    }
    return bcast_first(packed, packed);
}

// Wave0-only finish: subhist over both candidate segments, locate, tie-rank.
// Returns composite (low20<<12)|idx, or SENT (overflow), or 0 (m1==0).
template <bool fromTop>
__device__ unsigned wave_finish(unsigned* lds, unsigned m1) {
    const int lane = threadIdx.x & 63;
    unsigned* cand = lds + O_CAND;
    unsigned* hc   = lds + O_HC;
    unsigned* tiny = lds + O_TINY;
    const unsigned c0 = lds[O_CNT], c1 = lds[O_CNT + 1];
    if (m1 == 0) return 0u;
    if (c0 > CAPH || c1 > CAPH) return SENT;
    const unsigned cnt = c0 + c1;
#pragma unroll
    for (int i = 0; i < 4; ++i) hc[lane + 64 * i] = 0;
    for (unsigned i = lane; i < c0; i += 64) atomicAdd(&hc[cand[i] >> 24], 1u);
    for (unsigned i = lane; i < c1; i += 64) atomicAdd(&hc[cand[CAPH + i] >> 24], 1u);
    unsigned hh[4];
#pragma unroll
    for (int i = 0; i < 4; ++i) hh[i] = hc[4 * lane + i];
    const unsigned s4 = hh[0] + hh[1] + hh[2] + hh[3];
    unsigned run2 = wscan_incl(s4) - s4;
    unsigned packed2 = 0;
#pragma unroll
    for (int i = 0; i < 4; ++i) {
        if (fromTop) {
            const unsigned suf = cnt - run2 - hh[i];
            if (suf < m1 && m1 <= suf + hh[i])
                packed2 = ((unsigned)(4 * lane + i) << 16) | (m1 - suf);
        } else {
            if (run2 < m1 && m1 <= run2 + hh[i])
                packed2 = ((unsigned)(4 * lane + i) << 16) | (m1 - run2);
        }
        run2 += hh[i];
    }
    packed2 = bcast_first(packed2, packed2);
    if (packed2 == 0) return 0u;
    const unsigned b2 = packed2 >> 16;
    const unsigned m2 = packed2 & 0xFFFFu;
    unsigned tc = 0;
    for (unsigned i = lane; i < c0; i += 64) tc += ((cand[i] >> 24) == b2);
    for (unsigned i = lane; i < c1; i += 64) tc += ((cand[CAPH + i] >> 24) == b2);
    const unsigned tincl = wscan_incl(tc);
    const unsigned c2 = __shfl((int)tincl, 63, 64);
    if (c2 > CAP2) return SENT;
    unsigned tpos = tincl - tc;
    for (unsigned i = lane; i < c0; i += 64) {
        const unsigned cw = cand[i];
        if ((cw >> 24) == b2) tiny[tpos++] = cw;
    }
    for (unsigned i = lane; i < c1; i += 64) {
        const unsigned cw = cand[CAPH + i];
        if ((cw >> 24) == b2) tiny[tpos++] = cw;
    }
    unsigned hitf = 0, resv = 0;
    if ((unsigned)lane < c2) {
        const unsigned ci = tiny[lane];
        const unsigned di = fromTop ? (ci ^ 0xFFFu) : ci;
        unsigned r = 1;
        for (unsigned j = 0; j < c2; ++j) {
            const unsigned dj = fromTop ? (tiny[j] ^ 0xFFFu) : tiny[j];
            if (fromTop ? (dj > di) : (dj < di)) r++;
        }
        if (r == m2) { hitf = 1; resv = ci; }
    }
    return bcast_first(hitf, resv);
}

// Pathological fallback: bin-filtered counting rank over global row.
template <bool fromTop>
__device__ void block_fallback(const unsigned* __restrict__ gx,
                               unsigned b0, unsigned m1, unsigned* res) {
    const int t = threadIdx.x;
    for (int j = t; j < HW; j += NT) {
        const unsigned k = gx[j] & M31;
        if ((k >> 20) != b0) continue;
        unsigned Ci = ((k & 0xFFFFFu) << 12) | (unsigned)j;
        if (fromTop) Ci ^= 0xFFFu;
        unsigned r = 1;
        for (int j2 = 0; j2 < HW; ++j2) {
            const unsigned k2 = gx[j2] & M31;
            if ((k2 >> 20) != b0) continue;
            unsigned Cj = ((k2 & 0xFFFFFu) << 12) | (unsigned)j2;
            if (fromTop) Cj ^= 0xFFFu;
            if (fromTop ? (Cj > Ci) : (Cj < Ci)) r++;
        }
        if (r == m1) res[0] = ((k & 0xFFFFFu) << 12) | (unsigned)j;
    }
}

extern "C" __global__ void __launch_bounds__(NT, 6)
topk_kernel(const float* __restrict__ x, float* __restrict__ out) {
    __shared__ unsigned lds[LDSW];

    const int t = threadIdx.x;
    const int lane = t & 63;
    const int wid = t >> 6;
    const size_t row = blockIdx.x;
    const uint4* __restrict__ xin = (const uint4*)(x + row * HW);
    uint4* __restrict__ xo = (uint4*)(out + row * HW);
    const unsigned* __restrict__ gx = (const unsigned*)xin;
    const uint4 z4 = make_uint4(0u, 0u, 0u, 0u);

    // load row into registers; fence blocks rematerialization-as-reload
    uint4 v[6];
#pragma unroll
    for (int i = 0; i < 6; ++i) v[i] = xin[t + NT * i];
    uint4 vt = (t < 16) ? xin[768 + t] : z4;
#pragma unroll
    for (int i = 0; i < 6; ++i)
        asm volatile("" : "+v"(v[i].x), "+v"(v[i].y), "+v"(v[i].z), "+v"(v[i].w));
    asm volatile("" : "+v"(vt.x), "+v"(vt.y), "+v"(vt.z), "+v"(vt.w));

    // clear hist region (1088 words = 272 uint4)
    {
        uint4* h4 = (uint4*)(lds + O_H);
        h4[t] = z4; h4[t + NT] = z4;
        if (t < 16) h4[t + 2 * NT] = z4;
    }
    __syncthreads();                                         // B1

    // histogram from registers (abs bits 30:20)
#pragma unroll
    for (int i = 0; i < 6; ++i) {
        hadd(lds, (v[i].x & M31) >> 20); hadd(lds, (v[i].y & M31) >> 20);
        hadd(lds, (v[i].z & M31) >> 20); hadd(lds, (v[i].w & M31) >> 20);
    }
    if (t < 16) {
        hadd(lds, (vt.x & M31) >> 20); hadd(lds, (vt.y & M31) >> 20);
        hadd(lds, (vt.z & M31) >> 20); hadd(lds, (vt.w & M31) >> 20);
    }
    __syncthreads();                                         // B2

    // per-wave full CDF pull (conflict-free: addr 17*lane + j) + locate A
    unsigned pc[16];
#pragma unroll
    for (int j = 0; j < 16; ++j) pc[j] = lds[O_H + 17 * lane + j];
    unsigned ssum = 0;
#pragma unroll
    for (int j = 0; j < 16; ++j) ssum += (pc[j] & 0xFFFFu) + (pc[j] >> 16);
    const unsigned base = wscan_incl(ssum) - ssum;   // excl CDF of bin 32*lane
    const unsigned pA = locate2048<true>(pc, base, KSEL);
    const unsigned b0A = pA >> 16, m1A = pA & 0xFFFFu;

    // compact A into own wave segment (own counter; wave-internal ordering)
    unsigned* cseg = lds + O_CAND + wid * CAPH;
    unsigned* cctr = lds + O_CNT + wid;
    auto compact_regs = [&](unsigned b0) {
        auto cput = [&](unsigned wv, unsigned idx) {
            const unsigned k = wv & M31;
            if ((k >> 20) == b0) {
                const unsigned p = atomicAdd(cctr, 1u);
                if (p < CAPH) cseg[p] = ((k & 0xFFFFFu) << 12) | idx;
            }
        };
#pragma unroll
        for (int i = 0; i < 6; ++i) {
            const unsigned i0 = 4u * (unsigned)(t + NT * i);
            cput(v[i].x, i0); cput(v[i].y, i0 + 1u);
            cput(v[i].z, i0 + 2u); cput(v[i].w, i0 + 3u);
        }
        if (t < 16) {
            const unsigned i0 = 4u * (unsigned)(768 + t);
            cput(vt.x, i0); cput(vt.y, i0 + 1u);
            cput(vt.z, i0 + 2u); cput(vt.w, i0 + 3u);
        }
    };
    if (lane == 0) *cctr = 0;
    compact_regs(b0A);
    __syncthreads();                                         // B3

    if (wid == 0) {
        const unsigned r = wave_finish<true>(lds, m1A);
        if (lane == 0) lds[O_RES] = r;
    }
    __syncthreads();                                         // B4
    unsigned compA = lds[O_RES];
    if (compA == SENT) {
        block_fallback<true>(gx, b0A, m1A, lds + O_RES);
        __syncthreads();
        compA = lds[O_RES];
    }
    const unsigned tIdx = compA & 0xFFFu;

    // locate B: re-read intact hist (cand/hc/tiny live elsewhere)
#pragma unroll
    for (int j = 0; j < 16; ++j) pc[j] = lds[O_H + 17 * lane + j];
    const unsigned pB = locate2048<false>(pc, base, tIdx);   // 0 if tIdx==0
    const unsigned b0B = pB >> 16, m1B = pB & 0xFFFFu;

    if (lane == 0) *cctr = 0;
    compact_regs(b0B);
    __syncthreads();                                         // B5

    if (wid == 0) {
        const unsigned r = wave_finish<false>(lds, m1B);
        if (lane == 0) lds[O_RES] = r;
    }
    __syncthreads();                                         // B6
    unsigned compB = lds[O_RES];
    if (compB == SENT) {
        block_fallback<false>(gx, b0B, m1B, lds + O_RES);
        __syncthreads();
        compB = lds[O_RES];
    }
    const unsigned KB = (b0B << 20) | (compB >> 12);
    const unsigned eB = compB & 0xFFFu;

    // mask + store from registers: keep = k < KB || (k == KB && idx <= eB)
    {
        auto msk = [&](unsigned wv, unsigned idx) -> unsigned {
            const unsigned k = wv & M31;
            return (k < KB || (k == KB && idx <= eB)) ? wv : 0u;
        };
#pragma unroll
        for (int i = 0; i < 6; ++i) {
            const unsigned i0 = 4u * (unsigned)(t + NT * i);
            uint4 o = v[i];
            o.x = msk(o.x, i0); o.y = msk(o.y, i0 + 1u);
            o.z = msk(o.z, i0 + 2u); o.w = msk(o.w, i0 + 3u);
            xo[t + NT * i] = o;
        }
        if (t < 16) {
            const unsigned i0 = 4u * (unsigned)(768 + t);
            uint4 o = vt;
            o.x = msk(o.x, i0); o.y = msk(o.y, i0 + 1u);
            o.z = msk(o.z, i0 + 2u); o.w = msk(o.w, i0 + 3u);
            xo[768 + t] = o;
        }
    }
}

extern "C" void kernel_launch(void* const* d_in, const int* in_sizes, int n_in,
                              void* d_out, int out_size, void* d_ws, size_t ws_size,
                              hipStream_t stream) {
    const float* x = (const float*)d_in[0];
    float* out = (float*)d_out;
    const int rows = in_sizes[0] / HW;          // 8192
    topk_kernel<<<dim3(rows), dim3(NT), 0, stream>>>(x, out);
}